// Round 8
// baseline (117.786 us; speedup 1.0000x reference)
//
#include <hip/hip_runtime.h>

// MedianPool2d 3x3, stride 1, reflect pad, [8,8,512,512] fp32.
// R5 structure (dense 16B lane stride, NT stores, 4-slot rolling buffer,
// prefetch distance 1, scalar halo loads) with ONE change: 32 rows/thread
// (was 8) -> 512 blocks = 2/CU. Deep per-wave streams amortize the 3-row
// cold-start and cut cross-group row re-fetch from 2/10 to 2/34.

#define MP_W 512
#define MP_H 512

typedef float floatx4 __attribute__((ext_vector_type(4)));

__device__ __forceinline__ void mnmx(float& a, float& b) {
    const float t = fminf(a, b);
    b = fmaxf(a, b);
    a = t;
}

__device__ __forceinline__ float med3f(float a, float b, float c) {
    return fmaxf(fminf(a, b), fminf(fmaxf(a, b), c));
}

__global__ __launch_bounds__(256) void median3x3_kernel(const float* __restrict__ x,
                                                        float* __restrict__ out) {
    const int tid  = blockIdx.x * 256 + threadIdx.x;
    const int lane = tid & 63;
    const int wv   = tid >> 6;        // 0..2047
    const int hf   = wv & 1;          // which 256-col half of the row
    const int rg   = (wv >> 1) & 15;  // 32-row group within image
    const int bc   = wv >> 5;         // image 0..63
    const int y0   = rg << 5;
    const int x0   = (hf << 8) | (lane << 2);   // dense: lane-stride 16 B

    // reflect-adjusted halo offsets relative to rp = row base + x0
    const int off_l = (x0 == 0)        ? 1 : -1;   // -1 -> 1
    const int off_r = (x0 == MP_W - 4) ? 2 : 4;    // 512 -> 510

    const float* base  = x   + ((size_t)bc << 18);
    float*       obase = out + ((size_t)bc << 18) + (size_t)y0 * MP_W + x0;

    auto row_ptr = [&](int yy) -> const float* {
        yy = (yy < 0) ? -yy : (yy >= MP_H ? 2 * MP_H - 2 - yy : yy);  // reflect
        return base + (size_t)yy * MP_W + x0;
    };

    floatx4 bufV[4];            // cols x0..x0+3 of rows (y0-1+m), slot m&3
    float   bufL[4], bufR[4];   // halo cols x0-1, x0+4 (reflect-adjusted)

    #pragma unroll
    for (int k = 0; k < 3; ++k) {
        const float* rp = row_ptr(y0 - 1 + k);
        bufV[k] = *(const floatx4*)rp;
        bufL[k] = rp[off_l];
        bufR[k] = rp[off_r];
    }

    for (int rb = 0; rb < 8; ++rb) {
        #pragma unroll
        for (int q = 0; q < 4; ++q) {
            const int r = (rb << 2) + q;        // output row offset 0..31

            // prefetch input row y0+r+2 into the free slot (pure loads)
            if (r < 31) {
                const int s = (q + 3) & 3;      // == (r+3)&3, static
                const float* rp = row_ptr(y0 + r + 2);
                bufV[s] = *(const floatx4*)rp;
                bufL[s] = rp[off_l];
                bufR[s] = rp[off_r];
            }

            // window rows for output row y0+r: slots (r+k)&3 == (q+k)&3
            float v[3][6];
            #pragma unroll
            for (int k = 0; k < 3; ++k) {
                const int s = (q + k) & 3;
                const floatx4 a = bufV[s];
                v[k][0] = bufL[s];
                v[k][1] = a.x; v[k][2] = a.y; v[k][3] = a.z; v[k][4] = a.w;
                v[k][5] = bufR[s];
            }

            // sort each vertical column triple (shared by 3 horizontal windows)
            float lo[6], mi[6], hi[6];
            #pragma unroll
            for (int j = 0; j < 6; ++j) {
                float a = v[0][j], b = v[1][j], c = v[2][j];
                mnmx(a, b); mnmx(a, c); mnmx(b, c);
                lo[j] = a; mi[j] = b; hi[j] = c;
            }

            float res[4];
            #pragma unroll
            for (int j = 0; j < 4; ++j) {
                const float L = fmaxf(fmaxf(lo[j], lo[j + 1]), lo[j + 2]);
                const float M = med3f(mi[j], mi[j + 1], mi[j + 2]);
                const float H = fminf(fminf(hi[j], hi[j + 1]), hi[j + 2]);
                res[j] = med3f(L, M, H);
            }

            floatx4 o = {res[0], res[1], res[2], res[3]};
            __builtin_nontemporal_store(o, (floatx4*)(obase + (size_t)r * MP_W));
        }
    }
}

extern "C" void kernel_launch(void* const* d_in, const int* in_sizes, int n_in,
                              void* d_out, int out_size, void* d_ws, size_t ws_size,
                              hipStream_t stream) {
    const float* x = (const float*)d_in[0];
    float* out = (float*)d_out;
    // 128 outputs per thread (4 cols x 32 rows) -> 131072 threads -> 512 blocks
    const int n_threads = out_size / 128;
    const int block = 256;
    const int grid = n_threads / block;   // 512
    median3x3_kernel<<<grid, block, 0, stream>>>(x, out);
}

// Round 9
// 106.263 us; speedup vs baseline: 1.1084x; 1.1084x over previous
//
#include <hip/hip_runtime.h>

// MedianPool2d 3x3, stride 1, reflect pad, [8,8,512,512] fp32.
// R5 structure (dense 16B lane stride, 2048 blocks, NT stores, scalar halo
// loads) + ONE change: 2 output rows per iteration with a 6-slot rolling
// buffer and 2-row prefetch -> ~2 row-loads (2.2 KB) in flight per wave with
// 400-600 cyc of compute slack, covering HBM latency per Little's law.

#define MP_W 512
#define MP_H 512

typedef float floatx4 __attribute__((ext_vector_type(4)));

__device__ __forceinline__ void mnmx(float& a, float& b) {
    const float t = fminf(a, b);
    b = fmaxf(a, b);
    a = t;
}

__device__ __forceinline__ float med3f(float a, float b, float c) {
    return fmaxf(fminf(a, b), fminf(fmaxf(a, b), c));
}

__global__ __launch_bounds__(256) void median3x3_kernel(const float* __restrict__ x,
                                                        float* __restrict__ out) {
    const int tid  = blockIdx.x * 256 + threadIdx.x;
    const int lane = tid & 63;
    const int wv   = tid >> 6;        // 0..8191
    const int hf   = wv & 1;          // which 256-col half of the row
    const int rg   = (wv >> 1) & 63;  // 8-row group within image
    const int bc   = wv >> 7;         // image 0..63
    const int y0   = rg << 3;
    const int x0   = (hf << 8) | (lane << 2);   // dense: lane-stride 16 B

    // reflect-adjusted halo offsets relative to rp = row base + x0
    const int off_l = (x0 == 0)        ? 1 : -1;   // -1 -> 1
    const int off_r = (x0 == MP_W - 4) ? 2 : 4;    // 512 -> 510

    const float* base  = x   + ((size_t)bc << 18);
    float*       obase = out + ((size_t)bc << 18) + (size_t)y0 * MP_W + x0;

    auto row_ptr = [&](int yy) -> const float* {
        yy = (yy < 0) ? -yy : (yy >= MP_H ? 2 * MP_H - 2 - yy : yy);  // reflect
        return base + (size_t)yy * MP_W + x0;
    };

    // 6-slot rolling buffer: input row t (= y0-1+.. using t in -1..8) lives in
    // slot (t+1) % 6. All indices below are compile-time after unrolling.
    floatx4 bufV[6];
    float   bufL[6], bufR[6];

    #pragma unroll
    for (int t = -1; t <= 2; ++t) {   // prologue: 4 rows, slots 0..3
        const float* rp = row_ptr(y0 + t);
        bufV[t + 1] = *(const floatx4*)rp;
        bufL[t + 1] = rp[off_l];
        bufR[t + 1] = rp[off_r];
    }

    #pragma unroll
    for (int p = 0; p < 4; ++p) {     // each iteration: 2 output rows
        // prefetch input rows 2p+3, 2p+4 (first consumed next iteration)
        if (p < 3) {
            const int s1 = (2 * p + 4) % 6;
            const float* rp1 = row_ptr(y0 + 2 * p + 3);
            bufV[s1] = *(const floatx4*)rp1;
            bufL[s1] = rp1[off_l];
            bufR[s1] = rp1[off_r];
            const int s2 = (2 * p + 5) % 6;
            const float* rp2 = row_ptr(y0 + 2 * p + 4);
            bufV[s2] = *(const floatx4*)rp2;
            bufL[s2] = rp2[off_l];
            bufR[s2] = rp2[off_r];
        }

        #pragma unroll
        for (int q = 0; q < 2; ++q) { // output rows r = 2p, 2p+1
            const int r = 2 * p + q;

            float v[3][6];
            #pragma unroll
            for (int k = 0; k < 3; ++k) {
                const int s = (r + k) % 6;   // slot of input row r-1+k
                const floatx4 a = bufV[s];
                v[k][0] = bufL[s];
                v[k][1] = a.x; v[k][2] = a.y; v[k][3] = a.z; v[k][4] = a.w;
                v[k][5] = bufR[s];
            }

            // sort each vertical column triple (shared by 3 horizontal windows)
            float lo[6], mi[6], hi[6];
            #pragma unroll
            for (int j = 0; j < 6; ++j) {
                float a = v[0][j], b = v[1][j], c = v[2][j];
                mnmx(a, b); mnmx(a, c); mnmx(b, c);
                lo[j] = a; mi[j] = b; hi[j] = c;
            }

            float res[4];
            #pragma unroll
            for (int j = 0; j < 4; ++j) {
                const float L = fmaxf(fmaxf(lo[j], lo[j + 1]), lo[j + 2]);
                const float M = med3f(mi[j], mi[j + 1], mi[j + 2]);
                const float H = fminf(fminf(hi[j], hi[j + 1]), hi[j + 2]);
                res[j] = med3f(L, M, H);
            }

            floatx4 o = {res[0], res[1], res[2], res[3]};
            __builtin_nontemporal_store(o, (floatx4*)(obase + (size_t)r * MP_W));
        }
    }
}

extern "C" void kernel_launch(void* const* d_in, const int* in_sizes, int n_in,
                              void* d_out, int out_size, void* d_ws, size_t ws_size,
                              hipStream_t stream) {
    const float* x = (const float*)d_in[0];
    float* out = (float*)d_out;
    // 32 outputs per thread (4 cols x 8 rows) -> 524288 threads -> 2048 blocks
    const int n_threads = out_size / 32;
    const int block = 256;
    const int grid = n_threads / block;   // 2048
    median3x3_kernel<<<grid, block, 0, stream>>>(x, out);
}